// Round 13
// baseline (493.100 us; speedup 1.0000x reference)
//
#include <hip/hip_runtime.h>

using u16 = unsigned short;
using u32 = unsigned int;

typedef __bf16 bf16x8 __attribute__((ext_vector_type(8)));
typedef float  f32x4  __attribute__((ext_vector_type(4)));
typedef _Float16 f16;
typedef _Float16 f16x4 __attribute__((ext_vector_type(4)));
typedef _Float16 f16x8 __attribute__((ext_vector_type(8)));
typedef u16 u16x4 __attribute__((ext_vector_type(4)));

__device__ __forceinline__ float b2f(u16 u) { return __uint_as_float(((u32)u) << 16); }
__device__ __forceinline__ u16 f2b(float f) {
    u32 u = __float_as_uint(f);
    return (u16)((u + 0x7FFFu + ((u >> 16) & 1u)) >> 16);  // RNE
}

// async global->LDS, 16 B per lane.
__device__ __forceinline__ void async_cp16(void* lds, const void* g) {
    __builtin_amdgcn_global_load_lds(
        (const __attribute__((address_space(1))) u32*)g,
        (__attribute__((address_space(3))) u32*)lds, 16, 0, 0);
}

// fp32x4 -> (hi, lo) bf16 planes (bit-identical to old in-kernel split8)
__device__ __forceinline__ void split4_store(const float* src, u16* hi, u16* lo, int i) {
    f32x4 v = reinterpret_cast<const f32x4*>(src)[i];
    u16x4 H, L;
#pragma unroll
    for (int j = 0; j < 4; j++) {
        u16 hb = f2b(v[j]);
        H[j] = hb;
        L[j] = f2b(v[j] - b2f(hb));
    }
    reinterpret_cast<u16x4*>(hi)[i] = H;
    reinterpret_cast<u16x4*>(lo)[i] = L;
}

// ---------------------------------------------------------------------------
// Fused prep: x->f16; Wq->f16 hi/lo; Wp->f16; y->bf16 hi/lo; Wkv->bf16 hi/lo
// ---------------------------------------------------------------------------
__global__ __launch_bounds__(256) void prep(const float* __restrict__ x,
                                            const float* __restrict__ Wq,
                                            const float* __restrict__ Wp,
                                            const float* __restrict__ y,
                                            const float* __restrict__ Wkv,
                                            f16* __restrict__ xf,
                                            f16* __restrict__ wqhi, f16* __restrict__ wqlo,
                                            f16* __restrict__ wph,
                                            u16* __restrict__ yhi, u16* __restrict__ ylo,
                                            u16* __restrict__ wkhi, u16* __restrict__ wklo,
                                            int nx4, int nw4, int ny4, int nwk4) {
    int i = blockIdx.x * 256 + threadIdx.x;
    if (i < nx4) {
        f32x4 v = reinterpret_cast<const f32x4*>(x)[i];
        f16x4 h = {(f16)v[0], (f16)v[1], (f16)v[2], (f16)v[3]};
        reinterpret_cast<f16x4*>(xf)[i] = h;
    } else if (i < nx4 + nw4) {
        int k = i - nx4;
        f32x4 v = reinterpret_cast<const f32x4*>(Wq)[k];
        f16x4 H, L;
#pragma unroll
        for (int j = 0; j < 4; j++) {
            f16 hb = (f16)v[j];
            H[j] = hb;
            L[j] = (f16)(v[j] - (float)hb);
        }
        reinterpret_cast<f16x4*>(wqhi)[k] = H;
        reinterpret_cast<f16x4*>(wqlo)[k] = L;
    } else if (i < nx4 + 2 * nw4) {
        int k = i - nx4 - nw4;
        f32x4 v = reinterpret_cast<const f32x4*>(Wp)[k];
        f16x4 h = {(f16)v[0], (f16)v[1], (f16)v[2], (f16)v[3]};
        reinterpret_cast<f16x4*>(wph)[k] = h;
    } else if (i < nx4 + 2 * nw4 + ny4) {
        int k = i - nx4 - 2 * nw4;
        split4_store(y, yhi, ylo, k);
    } else {
        int k = i - nx4 - 2 * nw4 - ny4;
        if (k < nwk4) split4_store(Wkv, wkhi, wklo, k);
    }
}

// Bijective XCD-colocating remap for 428-block grids (107 m-tiles x 4 sg).
// The 4 sg blocks of one m-tile sit at blockIdx stride 8 -> same XCD L2.
__device__ __forceinline__ void remap428(int j, int& mt, int& sg) {
    if (j < 416) {
        int a = j >> 5, rem = j & 31;      // 13 groups of 32
        mt = a * 8 + (rem & 7);            // [0,103]
        sg = rem >> 3;                     // [0,3]
    } else {
        int rem = j - 416;                 // [0,12)
        mt = 104 + rem % 3;                // 104..106
        sg = rem / 3;                      // [0,3]
    }
}

// freqs for cross RoPE: 10000^(-f/16) = 10^(-f/4)
__constant__ double FREQS16[16] = {
    1.0, 0.5623413251903491, 0.31622776601683794, 0.17782794100389228,
    0.1, 0.05623413251903491, 0.03162277660168379, 0.017782794100389228,
    0.01, 0.005623413251903491, 0.0031622776601683794, 0.0017782794100389228,
    0.001, 0.0005623413251903491, 0.00031622776601683794, 0.00017782794100389228};

// ---------------------------------------------------------------------------
// FUSED q + kv projections. kv path unchanged (blocks 0..287).
// Q path (blocks 288+): 128-ROW m-tiles — the guide-ladder m92->m93 step.
// Evidence: q ran at 384 TF = the 64-tile 2-barrier structure's ceiling
// (work/barrier/TLP changes all null). 128-row tiles double MFMA per staged
// byte and per barrier: acc[8][4], 64 KB LDS (2 blocks/CU, VGPR-matched),
// 107 m-tiles x 4 head-groups = 428 q-blocks (remap428 XCD colocation).
// Per-element accumulation order identical -> bit-identical q and k/v.
// M=13632 = 106.5*128: last tile half-valid, epilogue row-guarded (OOB
// staging reads land in the adjacent allocated planes and are discarded;
// shfl groups are row-homogeneous so no cross-row contamination).
// ---------------------------------------------------------------------------
__global__ __launch_bounds__(256) void qkv(const f16* __restrict__ xf,
                                           const f16* __restrict__ whi,
                                           const f16* __restrict__ wlo,
                                           const float* __restrict__ qb,
                                           const float* __restrict__ fc,
                                           const float* __restrict__ smul,
                                           f16* __restrict__ qout,
                                           const u16* __restrict__ yhi,
                                           const u16* __restrict__ ylo,
                                           const u16* __restrict__ wkhi,
                                           const u16* __restrict__ wklo,
                                           const float* __restrict__ vb,
                                           f16* __restrict__ khp,
                                           f16* __restrict__ klp,
                                           f16* __restrict__ vhp,
                                           f16* __restrict__ vlp) {
    const int K = 1024, L = 1704, M = 13632;
    __shared__ f16 xs[2][2][128][64];  // [buf][khalf][row][k] = 64 KB (swizzled)
    int tid = threadIdx.x;
    int lane = tid & 63, wv = tid >> 6;
    int lr = lane & 15, quad = lane >> 4;

    if (blockIdx.x < 288) {
        // ------------------------- KV path (round-9) -------------------------
        int mt = blockIdx.x >> 3;            // [0,36)
        int nt = (blockIdx.x & 7) * 4 + wv;  // [0,32)
        long m0 = (long)mt * 32;

        const bf16x8* ah_p[2];
        const bf16x8* al_p[2];
        const bf16x8* wh_p[4];
        const bf16x8* wl_p[4];
#pragma unroll
        for (int i = 0; i < 2; i++) {
            long aoff = (m0 + i * 16 + lr) * K;
            ah_p[i] = reinterpret_cast<const bf16x8*>(yhi + aoff) + quad;
            al_p[i] = reinterpret_cast<const bf16x8*>(ylo + aoff) + quad;
        }
#pragma unroll
        for (int i = 0; i < 4; i++) {
            long woff = ((long)(nt * 64 + i * 16 + lr)) * K;
            wh_p[i] = reinterpret_cast<const bf16x8*>(wkhi + woff) + quad;
            wl_p[i] = reinterpret_cast<const bf16x8*>(wklo + woff) + quad;
        }

        f32x4 acc[2][4] = {};
        for (int ks = 0; ks < 32; ks++) {
            int o = ks * 4;
            bf16x8 ah[2], al[2], wh[4], wl[4];
#pragma unroll
            for (int i = 0; i < 2; i++) { ah[i] = ah_p[i][o]; al[i] = al_p[i][o]; }
#pragma unroll
            for (int i = 0; i < 4; i++) { wh[i] = wh_p[i][o]; wl[i] = wl_p[i][o]; }
#pragma unroll
            for (int mi = 0; mi < 2; mi++)
#pragma unroll
                for (int ni = 0; ni < 4; ni++) {
                    acc[mi][ni] = __builtin_amdgcn_mfma_f32_16x16x32_bf16(ah[mi], wh[ni], acc[mi][ni], 0, 0, 0);
                    acc[mi][ni] = __builtin_amdgcn_mfma_f32_16x16x32_bf16(al[mi], wh[ni], acc[mi][ni], 0, 0, 0);
                    acc[mi][ni] = __builtin_amdgcn_mfma_f32_16x16x32_bf16(ah[mi], wl[ni], acc[mi][ni], 0, 0, 0);
                }
        }

        bool isv = nt >= 16;
        int h = isv ? nt - 16 : nt;
#pragma unroll
        for (int mi = 0; mi < 2; mi++) {
#pragma unroll
            for (int r = 0; r < 4; r++) {
                long row = m0 + mi * 16 + quad * 4 + r;  // [0,1152)
                int b = (int)(row / 144), lk = (int)(row % 144);
                long bh = b * 16 + h;
                float v[4];
#pragma unroll
                for (int ni = 0; ni < 4; ni++)
                    v[ni] = acc[mi][ni][r] + (isv ? vb[h * 64 + ni * 16 + lr] : 0.f);
                if (!isv) {
                    float ss = v[0] * v[0] + v[1] * v[1] + v[2] * v[2] + v[3] * v[3];
                    ss += __shfl_xor(ss, 1, 64); ss += __shfl_xor(ss, 2, 64);
                    ss += __shfl_xor(ss, 4, 64); ss += __shfl_xor(ss, 8, 64);
                    float inv = 1.f / fmaxf(sqrtf(ss), 1e-12f);
                    f16* kh_row = khp + (bh * 144 + lk) * 64;
                    f16* kl_row = klp + (bh * 144 + lk) * 64;
#pragma unroll
                    for (int ni = 0; ni < 4; ni++) {
                        float u = v[ni] * inv;
                        int d = ni * 16 + lr;
                        int j = d >> 1;
                        int f = j & 15;
                        float tc = (j < 16) ? ((float)(lk / 12)) / 12.0f * 32.0f
                                            : ((float)(lk % 12)) / 12.0f * 32.0f;
                        float ang = (float)((double)tc * FREQS16[f]);
                        float c = cosf(ang), s = sinf(ang);
                        float pr = __shfl_xor(u, 1, 64);
                        float o = (lane & 1) ? (pr * s + u * c) : (u * c - pr * s);
                        f16 oh = (f16)o;
                        f16 ol = (f16)(o - (float)oh);
                        kh_row[d] = oh;
                        kl_row[d] = ol;
                    }
                } else {
#pragma unroll
                    for (int ni = 0; ni < 4; ni++) {
                        float val = v[ni];
                        int d = ni * 16 + lr;
                        f16 vh = (f16)val;
                        f16 vl = (f16)(val - (float)vh);
                        vhp[(bh * 64 + d) * 144 + lk] = vh;
                        vlp[(bh * 64 + d) * 144 + lk] = vl;
                    }
                }
            }
        }
        return;
    }

    // ---------------- Q path (128-row tiles) ----------------
    int mt, hg;
    remap428(blockIdx.x - 288, mt, hg);
    int h  = hg * 4 + wv;
    long m0 = (long)mt * 128;

    // staging: per khalf, 1024 slots of 16B; thread t covers slots t+256k,
    // k=0..3 -> rows r0+32k (32k = 0 mod 8, so the col swizzle is constant).
    int r0 = tid >> 3, c0 = tid & 7;
    const f16* srcx0 = xf + (m0 + r0) * K + ((c0 ^ (r0 & 7)) * 8);

    const f16x8* wh_p[4];
    const f16x8* wl_p[4];
#pragma unroll
    for (int i = 0; i < 4; i++) {
        long woff = ((long)(h * 64 + i * 16 + lr)) * K;
        wh_p[i] = reinterpret_cast<const f16x8*>(whi + woff) + quad;
        wl_p[i] = reinterpret_cast<const f16x8*>(wlo + woff) + quad;
    }

    int sp0 = ((0 + quad) ^ (lr & 7)) * 8;
    int sp1 = ((4 + quad) ^ (lr & 7)) * 8;

    f32x4 acc[8][4] = {};

    // prologue: stage super-chunk 0 into buf 0 (both halves, 4 rows-strides)
#pragma unroll
    for (int hh = 0; hh < 2; hh++)
#pragma unroll
        for (int k4 = 0; k4 < 4; k4++)
            async_cp16(&xs[0][hh][r0 + 32 * k4][c0 * 8], srcx0 + hh * 64 + (long)(32 * k4) * K);
    __syncthreads();

    for (int c = 0; c < 8; c++) {
        if (c < 7) {
            int nb = (c + 1) & 1;
            int off = (c + 1) * 128;
#pragma unroll
            for (int hh = 0; hh < 2; hh++)
#pragma unroll
                for (int k4 = 0; k4 < 4; k4++)
                    async_cp16(&xs[nb][hh][r0 + 32 * k4][c0 * 8],
                               srcx0 + off + hh * 64 + (long)(32 * k4) * K);
        }
        int buf = c & 1;
#pragma unroll
        for (int hh = 0; hh < 2; hh++) {
#pragma unroll
            for (int s = 0; s < 2; s++) {
                int o = (c * 2 + hh) * 8 + s * 4;
                int sp = s ? sp1 : sp0;
                f16x8 WH[4], WL[4];
#pragma unroll
                for (int i = 0; i < 4; i++) {
                    WH[i] = wh_p[i][o];
                    WL[i] = wl_p[i][o];
                }
#pragma unroll
                for (int mi = 0; mi < 8; mi++) {
                    f16x8 AF = *reinterpret_cast<const f16x8*>(&xs[buf][hh][mi * 16 + lr][sp]);
#pragma unroll
                    for (int ni = 0; ni < 4; ni++) {
                        acc[mi][ni] = __builtin_amdgcn_mfma_f32_16x16x32_f16(AF, WH[ni], acc[mi][ni], 0, 0, 0);
                        acc[mi][ni] = __builtin_amdgcn_mfma_f32_16x16x32_f16(AF, WL[ni], acc[mi][ni], 0, 0, 0);
                    }
                }
            }
        }
        __syncthreads();  // waves done reading buf; staged c+1 drained
    }

    float sm = __expf(fminf(smul[h], 4.6051702f));  // ln(100)
#pragma unroll
    for (int mi = 0; mi < 8; mi++) {
#pragma unroll
        for (int r = 0; r < 4; r++) {
            long rowg = m0 + mi * 16 + quad * 4 + r;
            float v[4];
            float ss = 0.f;
#pragma unroll
            for (int ni = 0; ni < 4; ni++) {
                v[ni] = acc[mi][ni][r] + qb[h * 64 + ni * 16 + lr];
                ss += v[ni] * v[ni];
            }
            ss += __shfl_xor(ss, 1, 64); ss += __shfl_xor(ss, 2, 64);
            ss += __shfl_xor(ss, 4, 64); ss += __shfl_xor(ss, 8, 64);
            float inv = sm / fmaxf(sqrtf(ss), 1e-12f);
            int l = (int)(rowg % L);
            f16* orow = qout + rowg * 1024 + h * 64;
            if (rowg < M) {
#pragma unroll
                for (int ni = 0; ni < 4; ni++) {
                    float u = v[ni] * inv;
                    int d = ni * 16 + lr;
                    int j = d >> 1;
                    float cc = fc[(l * 32 + j) * 2];
                    float s = fc[(l * 32 + j) * 2 + 1];
                    float pr = __shfl_xor(u, 1, 64);
                    float o = (lane & 1) ? (pr * s + u * cc) : (u * cc - pr * s);
                    orow[d] = (f16)o;
                }
            } else {
                // keep shfl lock-step for the RoPE pair exchange
#pragma unroll
                for (int ni = 0; ni < 4; ni++) {
                    float u = v[ni] * inv;
                    (void)__shfl_xor(u, 1, 64);
                }
            }
        }
    }
}

// ---------------------------------------------------------------------------
// MFMA attention (round-9 best). Block = 4 indep waves, no barriers.
// ---------------------------------------------------------------------------
__global__ __launch_bounds__(256, 3) void attn(const f16* q,
                                               const f16* __restrict__ khp,
                                               const f16* __restrict__ klp,
                                               const f16* __restrict__ vhp,
                                               const f16* __restrict__ vlp,
                                               const float* __restrict__ abias,
                                               f16* aout) {
    const int L = 1704;
    __shared__ __align__(16) f16 ps[4][16][152];  // 19.5 KB, per-wave regions
    int tid = threadIdx.x;
    int lane = tid & 63, wv = tid >> 6;
    int lr = lane & 15, quad = lane >> 4;
    int ltile = blockIdx.x % 27;
    int bh = blockIdx.x / 27;  // b*16+h
    int h = bh & 15, b = bh >> 4;
    int l0 = ltile * 64;
    int rows = min(64, L - l0);  // 64 or 40 (tail)

    int rA = wv * 16 + lr;
    int rAc = min(rA, rows - 1);
    const f16* qrow = q + ((long)(b * L + l0 + rAc)) * 1024 + h * 64;
    f16x8 qa0 = *reinterpret_cast<const f16x8*>(qrow + quad * 8);
    f16x8 qa1 = *reinterpret_cast<const f16x8*>(qrow + 32 + quad * 8);

    const f16* khb = khp + (long)bh * (144 * 64);
    const f16* klb = klp + (long)bh * (144 * 64);

    f32x4 acc[9] = {};
#pragma unroll
    for (int t = 0; t < 9; t++) {
        const f16* k0 = khb + (t * 16 + lr) * 64 + quad * 8;
        const f16* k1 = klb + (t * 16 + lr) * 64 + quad * 8;
        f16x8 bh0 = *reinterpret_cast<const f16x8*>(k0);
        f16x8 bh1 = *reinterpret_cast<const f16x8*>(k0 + 32);
        f16x8 bl0 = *reinterpret_cast<const f16x8*>(k1);
        f16x8 bl1 = *reinterpret_cast<const f16x8*>(k1 + 32);
        __builtin_amdgcn_s_setprio(1);
        acc[t] = __builtin_amdgcn_mfma_f32_16x16x32_f16(qa0, bh0, acc[t], 0, 0, 0);
        acc[t] = __builtin_amdgcn_mfma_f32_16x16x32_f16(qa1, bh1, acc[t], 0, 0, 0);
        acc[t] = __builtin_amdgcn_mfma_f32_16x16x32_f16(qa0, bl0, acc[t], 0, 0, 0);
        acc[t] = __builtin_amdgcn_mfma_f32_16x16x32_f16(qa1, bl1, acc[t], 0, 0, 0);
        __builtin_amdgcn_s_setprio(0);
    }

    int rC = wv * 16 + quad * 4;
#pragma unroll
    for (int r = 0; r < 4; r++) {
        long lrow = (long)(l0 + min(rC + r, rows - 1)) * 144;
#pragma unroll
        for (int t = 0; t < 9; t++) acc[t][r] += abias[lrow + t * 16 + lr];
    }

#pragma unroll
    for (int r = 0; r < 4; r++) {
        float mx = acc[0][r];
#pragma unroll
        for (int t = 1; t < 9; t++) mx = fmaxf(mx, acc[t][r]);
        mx = fmaxf(mx, __shfl_xor(mx, 1, 64));
        mx = fmaxf(mx, __shfl_xor(mx, 2, 64));
        mx = fmaxf(mx, __shfl_xor(mx, 4, 64));
        mx = fmaxf(mx, __shfl_xor(mx, 8, 64));
        float s = 0.f;
#pragma unroll
        for (int t = 0; t < 9; t++) {
            float e = __expf(acc[t][r] - mx);
            acc[t][r] = e;
            s += e;
        }
        s += __shfl_xor(s, 1, 64);
        s += __shfl_xor(s, 2, 64);
        s += __shfl_xor(s, 4, 64);
        s += __shfl_xor(s, 8, 64);
        float inv = 1.0f / s;
#pragma unroll
        for (int t = 0; t < 9; t++)
            ps[wv][quad * 4 + r][t * 16 + lr] = (f16)(acc[t][r] * inv);
    }

    const f16* vhb = vhp + (long)bh * (64 * 144);
    const f16* vlb = vlp + (long)bh * (64 * 144);
    f32x4 oacc[4] = {};
#pragma unroll
    for (int ks = 0; ks < 5; ks++) {
        f16x8 pa = {0, 0, 0, 0, 0, 0, 0, 0};
        if (ks < 4 || quad < 2)
            pa = *reinterpret_cast<const f16x8*>(&ps[wv][lr][ks * 32 + quad * 8]);
#pragma unroll
        for (int n = 0; n < 4; n++) {
            f16x8 vh8 = {0, 0, 0, 0, 0, 0, 0, 0};
            f16x8 vl8 = {0, 0, 0, 0, 0, 0, 0, 0};
            if (ks < 4 || quad < 2) {
                const f16* vr  = vhb + (n * 16 + lr) * 144 + ks * 32 + quad * 8;
                const f16* vr2 = vlb + (n * 16 + lr) * 144 + ks * 32 + quad * 8;
                vh8 = *reinterpret_cast<const f16x8*>(vr);
                vl8 = *reinterpret_cast<const f16x8*>(vr2);
            }
            __builtin_amdgcn_s_setprio(1);
            oacc[n] = __builtin_amdgcn_mfma_f32_16x16x32_f16(pa, vh8, oacc[n], 0, 0, 0);
            oacc[n] = __builtin_amdgcn_mfma_f32_16x16x32_f16(pa, vl8, oacc[n], 0, 0, 0);
            __builtin_amdgcn_s_setprio(0);
        }
    }

    long ob = (long)(b * L + l0);
#pragma unroll
    for (int r = 0; r < 4; r++) {
        int rw = rC + r;
        if (rw < rows) {
            f16* ao = aout + (ob + rw) * 1024 + h * 64;
#pragma unroll
            for (int n = 0; n < 4; n++) ao[n * 16 + lr] = (f16)oacc[n][r];
        }
    }
}

// ---------------------------------------------------------------------------
// Final projection, 128-ROW m-tiles (same ladder step as the q path):
// acc[8][4], 64 KB LDS, 428 blocks (remap428), BK=128, W f16 direct.
// Epilogue row-guarded for the half-valid last tile. fp32 out.
// ---------------------------------------------------------------------------
__global__ __launch_bounds__(256) void gemm_proj(const f16* __restrict__ A,
                                                 const f16* __restrict__ Wh,
                                                 const float* __restrict__ bias,
                                                 float* __restrict__ out) {
    const int K = 1024, M = 13632;
    __shared__ f16 as[2][2][128][64];  // [buf][khalf][row][k] = 64 KB (swizzled)
    int tid = threadIdx.x;
    int lane = tid & 63, wv = tid >> 6;
    int mt, cg;
    remap428(blockIdx.x, mt, cg);
    int lr = lane & 15, quad = lane >> 4;
    long m0 = (long)mt * 128;
    long n0 = (long)cg * 256 + wv * 64;

    int r0 = tid >> 3, c0 = tid & 7;
    const f16* srca0 = A + (m0 + r0) * K + ((c0 ^ (r0 & 7)) * 8);

    const f16x8* wrow[4];
#pragma unroll
    for (int i = 0; i < 4; i++)
        wrow[i] = reinterpret_cast<const f16x8*>(Wh + (n0 + i * 16 + lr) * K) + quad;

    int sp0 = ((0 + quad) ^ (lr & 7)) * 8;
    int sp1 = ((4 + quad) ^ (lr & 7)) * 8;

    f32x4 acc[8][4] = {};

#pragma unroll
    for (int hh = 0; hh < 2; hh++)
#pragma unroll
        for (int k4 = 0; k4 < 4; k4++)
            async_cp16(&as[0][hh][r0 + 32 * k4][c0 * 8], srca0 + hh * 64 + (long)(32 * k4) * K);
    __syncthreads();

    for (int c = 0; c < 8; c++) {
        if (c < 7) {
            int nb = (c + 1) & 1;
            int off = (c + 1) * 128;
#pragma unroll
            for (int hh = 0; hh < 2; hh++)
#pragma unroll
                for (int k4 = 0; k4 < 4; k4++)
                    async_cp16(&as[nb][hh][r0 + 32 * k4][c0 * 8],
                               srca0 + off + hh * 64 + (long)(32 * k4) * K);
        }
        int buf = c & 1;
#pragma unroll
        for (int hh = 0; hh < 2; hh++) {
#pragma unroll
            for (int s = 0; s < 2; s++) {
                int o = (c * 2 + hh) * 8 + s * 4;
                int sp = s ? sp1 : sp0;
                f16x8 wf[4];
#pragma unroll
                for (int i = 0; i < 4; i++) wf[i] = wrow[i][o];
#pragma unroll
                for (int mi = 0; mi < 8; mi++) {
                    f16x8 af = *reinterpret_cast<const f16x8*>(&as[buf][hh][mi * 16 + lr][sp]);
#pragma unroll
                    for (int ni = 0; ni < 4; ni++)
                        acc[mi][ni] = __builtin_amdgcn_mfma_f32_16x16x32_f16(af, wf[ni], acc[mi][ni], 0, 0, 0);
                }
            }
        }
        __syncthreads();
    }

#pragma unroll
    for (int ni = 0; ni < 4; ni++) {
        int col = (int)n0 + ni * 16 + lr;
        float b = bias[col];
#pragma unroll
        for (int mi = 0; mi < 8; mi++) {
            long row = m0 + mi * 16 + quad * 4;
#pragma unroll
            for (int r = 0; r < 4; r++)
                if (row + r < M) out[(row + r) * 1024 + col] = acc[mi][ni][r] + b;
        }
    }
}

extern "C" void kernel_launch(void* const* d_in, const int* in_sizes, int n_in,
                              void* d_out, int out_size, void* d_ws, size_t ws_size,
                              hipStream_t stream) {
    const float* x     = (const float*)d_in[0];
    const float* y     = (const float*)d_in[1];
    const float* fc    = (const float*)d_in[2];
    const float* abias = (const float*)d_in[3];
    const float* Wq    = (const float*)d_in[4];
    const float* qb    = (const float*)d_in[5];
    const float* Wkv   = (const float*)d_in[6];
    const float* vb    = (const float*)d_in[7];
    const float* Wp    = (const float*)d_in[8];
    const float* bp    = (const float*)d_in[9];
    const float* smul  = (const float*)d_in[10];

    const long XN  = 13959168L;  // 8*1704*1024
    const long WN  = 1048576L;   // 1024*1024
    const long YN  = 1179648L;   // 8*144*1024
    const long WKN = 2097152L;   // 2048*1024
    const long KVN = 1179648L;   // 128*144*64 (= 128*64*144)

    // d_ws layout (33.9 MB): qbuf fp16 | Wq hi f16 | Wq lo f16 | Wp fp16
    f16* qbuf  = (f16*)d_ws;
    f16* wq_hi = qbuf + XN;
    f16* wq_lo = wq_hi + WN;
    f16* wp_h  = wq_lo + WN;

    // d_out (55.8 MB), 50.4 MB used:
    //   x f16 (27.9) | y bf16 hi/lo (4.7) | Wkv bf16 hi/lo (8.4) | K/V planes (9.4)
    // K/V planes AFTER the Wkv planes because the fused qkv kernel writes
    // them while q-blocks still read x_f (no aliasing). All dead before
    // gemm_proj overwrites d_out with the fp32 output.
    f16* x_f   = (f16*)d_out;
    u16* y_hi  = (u16*)(x_f + XN);
    u16* y_lo  = y_hi + YN;
    u16* wk_hi = y_lo + YN;
    u16* wk_lo = wk_hi + WKN;
    f16* kh_p  = (f16*)(wk_lo + WKN);
    f16* kl_p  = kh_p + KVN;
    f16* vth_p = kl_p + KVN;
    f16* vtl_p = vth_p + KVN;

    int nx4  = (int)(XN / 4);
    int nw4  = (int)(WN / 4);
    int ny4  = (int)(YN / 4);
    int nwk4 = (int)(WKN / 4);
    int prep_blocks = (nx4 + 2 * nw4 + ny4 + nwk4 + 255) / 256;

    prep<<<dim3(prep_blocks), dim3(256), 0, stream>>>(
        x, Wq, Wp, y, Wkv, x_f, wq_hi, wq_lo, wp_h,
        y_hi, y_lo, wk_hi, wk_lo, nx4, nw4, ny4, nwk4);
    qkv<<<dim3(288 + 428), dim3(256), 0, stream>>>(
        x_f, wq_hi, wq_lo, qb, fc, smul, qbuf,
        y_hi, y_lo, wk_hi, wk_lo, vb, kh_p, kl_p, vth_p, vtl_p);
    attn<<<dim3(3456), dim3(256), 0, stream>>>(qbuf, kh_p, kl_p, vth_p, vtl_p, abias, (f16*)qbuf);
    gemm_proj<<<dim3(428), dim3(256), 0, stream>>>((const f16*)qbuf, wp_h, bp, (float*)d_out);
}